// Round 5
// baseline (254.784 us; speedup 1.0000x reference)
//
#include <hip/hip_runtime.h>
#include <hip/hip_bf16.h>

#define B_ 64
#define J_ 2048
#define K_ 32
#define D_ 16
#define KD 512
#define CHB 128      // k_B j-chunks (spart partials)
#define JCB 16       // j's per k_B chunk
#define JCA 2        // j's per k_A block

typedef __attribute__((ext_vector_type(8))) short short8v;   // 8 bf16 (4 VGPR)
typedef __attribute__((ext_vector_type(4))) float f32x4;     // 4 f32 acc

__device__ __forceinline__ float bf2f(unsigned int bits16) {
  unsigned int u = bits16 << 16;
  return __builtin_bit_cast(float, u);
}
__device__ __forceinline__ unsigned int f2bf(float f) {
  unsigned int u = __builtin_bit_cast(unsigned int, f);
  u = u + 0x7fffu + ((u >> 16) & 1u);   // round-to-nearest-even
  return u >> 16;
}
__device__ __forceinline__ short8v mk_frag(unsigned int d0, unsigned int d1) {
  uint4 t = make_uint4(d0, d1, 0u, 0u);        // k-slots 4..7 zero
  return __builtin_bit_cast(short8v, t);
}

// ---------------- prep: WB[j][k][d][i] = bf16(W[k][j][d][i]);  XT[j][b][i] = bf16(x[b][j][i])
__global__ __launch_bounds__(256) void k_prep(const float* __restrict__ inp,
                                              const float* __restrict__ W,
                                              unsigned short* __restrict__ WB,
                                              unsigned short* __restrict__ XT) {
  const size_t tid = (size_t)blockIdx.x * 256 + threadIdx.x;
  const size_t stride = (size_t)gridDim.x * 256;
  // W: 16,777,216 elems, 8 per thread
  for (size_t g8 = tid; g8 < (size_t)J_ * K_ * 32; g8 += stride) {
    const size_t o = g8 * 8;
    const int j = (int)(o >> 13), k = (int)((o >> 8) & 31), di = (int)(o & 255);
    const float* src = W + ((size_t)k * J_ + j) * 256 + di;
    const float4 a = *(const float4*)src;
    const float4 b = *(const float4*)(src + 4);
    uint4 pk;
    pk.x = f2bf(a.x) | (f2bf(a.y) << 16);
    pk.y = f2bf(a.z) | (f2bf(a.w) << 16);
    pk.z = f2bf(b.x) | (f2bf(b.y) << 16);
    pk.w = f2bf(b.z) | (f2bf(b.w) << 16);
    *(uint4*)(WB + o) = pk;
  }
  // x: 2,097,152 elems, 8 per thread
  for (size_t g8 = tid; g8 < (size_t)J_ * B_ * 2; g8 += stride) {
    const size_t o = g8 * 8;
    const int j = (int)(o >> 10), b = (int)((o >> 4) & 63), i0 = (int)(o & 15);
    const float* src = inp + ((size_t)b * J_ + j) * 16 + i0;
    const float4 a = *(const float4*)src;
    const float4 c = *(const float4*)(src + 4);
    uint4 pk;
    pk.x = f2bf(a.x) | (f2bf(a.y) << 16);
    pk.y = f2bf(a.z) | (f2bf(a.w) << 16);
    pk.z = f2bf(c.x) | (f2bf(c.y) << 16);
    pk.w = f2bf(c.z) | (f2bf(c.w) << 16);
    *(uint4*)(XT + o) = pk;
  }
}

// ---------------- k_A: compute c[b][j][k] = softmax_k(osum . u_hat). One block = 2 j's,
// 4 waves = 4 b-groups. Per wave-j: 32 MFMAs -> u in regs; dot with reg-resident bf16
// osum; in-lane softmax (p replicated via 2 shuffles); store c f32 [j][b][k].
// WRITEC: also write c to outp (final-iteration c) via padded LDS transpose.
template <int WRITEC>
__global__ __launch_bounds__(256) void k_A(const unsigned short* __restrict__ XT,
                                           const unsigned short* __restrict__ WB,
                                           const unsigned short* __restrict__ osum_bf,
                                           float* __restrict__ cB,
                                           float* __restrict__ outp) {
  const int jb = blockIdx.x;                     // j = jb*2 + jc
  const int t = threadIdx.x;
  const int wave = t >> 6, lane = t & 63;
  const int g = lane >> 4, r = lane & 15;
  const int b = wave * 16 + r;

  __shared__ float cbuf[WRITEC ? JCA * B_ * 33 : 4];

  // reg-resident osum (bf16 packed): os_pk[k] = kd = k*16 + 4g + {0..3}
  uint2 os_pk[32];
  {
    const unsigned short* ob = osum_bf + b * KD + 4 * g;
#pragma unroll
    for (int k = 0; k < 32; ++k) os_pk[k] = *(const uint2*)(ob + k * 16);
  }

#pragma unroll
  for (int jc = 0; jc < JCA; ++jc) {
    const int j = jb * JCA + jc;
    const uint2 xv = *(const uint2*)(XT + ((size_t)j * 64 + b) * 16 + 4 * g);
    const short8v bfr = mk_frag(xv.x, xv.y);
    const unsigned short* wj = WB + (size_t)j * 8192 + r * 16 + 4 * g;

    float p[32];
#pragma unroll
    for (int k = 0; k < 32; ++k) {
      const uint2 wv = *(const uint2*)(wj + k * 256);
      const f32x4 u = __builtin_amdgcn_mfma_f32_16x16x32_bf16(
          mk_frag(wv.x, wv.y), bfr, (f32x4){0.f, 0.f, 0.f, 0.f}, 0, 0, 0);
      float pp;
      pp = u[0] * bf2f(os_pk[k].x & 0xffffu);
      pp = fmaf(u[1], bf2f(os_pk[k].x >> 16), pp);
      pp = fmaf(u[2], bf2f(os_pk[k].y & 0xffffu), pp);
      pp = fmaf(u[3], bf2f(os_pk[k].y >> 16), pp);
      p[k] = pp;
    }
#pragma unroll
    for (int k = 0; k < 32; ++k) {
      p[k] += __shfl_xor(p[k], 16);
      p[k] += __shfl_xor(p[k], 32);     // p replicated: full dot over d for (b, k)
    }
    // in-lane softmax over 32 k (logits O(±8): skip max-subtraction, shift-invariant)
    float e[32];
#pragma unroll
    for (int k = 0; k < 32; ++k) e[k] = __expf(p[k]);
    float q[8];
#pragma unroll
    for (int h = 0; h < 8; ++h) q[h] = (e[4 * h] + e[4 * h + 1]) + (e[4 * h + 2] + e[4 * h + 3]);
    const float S = ((q[0] + q[1]) + (q[2] + q[3])) + ((q[4] + q[5]) + (q[6] + q[7]));
    const float rS = __builtin_amdgcn_rcpf(S);

    if (g == 0) {                       // c replicated across g; one g-slice stores
      float* cp = cB + ((size_t)j * 64 + b) * 32;
#pragma unroll
      for (int h = 0; h < 8; ++h) {
        *(float4*)(cp + 4 * h) = make_float4(e[4 * h] * rS, e[4 * h + 1] * rS,
                                             e[4 * h + 2] * rS, e[4 * h + 3] * rS);
      }
      if constexpr (WRITEC) {
        float* cb = &cbuf[(jc * 64 + b) * 33];
#pragma unroll
        for (int k = 0; k < 32; ++k) cb[k] = e[k] * rS;
      }
    }
  }

  if constexpr (WRITEC) {
    __syncthreads();
#pragma unroll
    for (int it = 0; it < 8; ++it) {
      const int row = it * 256 + t;     // (b,k) row
      const int b2 = row >> 5, k2 = row & 31;
      const float v0 = cbuf[(b2)*33 + k2];
      const float v1 = cbuf[(64 + b2) * 33 + k2];
      *(float2*)(outp + ((size_t)b2 * K_ + k2) * 2064 + 16 + jb * JCA) = make_float2(v0, v1);
    }
  }
}

// ---------------- k_B: s[b][kd] partials via MFMA with c folded into B-frag.
// block = (chunk, k), 4 waves = 4 b-groups. Wave accumulates 16 j's in its C-regs.
// CMODE 0: c = 1/32 (applied at store). CMODE 1: B' = bf16(x * c).
template <int CMODE>
__global__ __launch_bounds__(256) void k_B(const unsigned short* __restrict__ XT,
                                           const unsigned short* __restrict__ WB,
                                           const float* __restrict__ cB,
                                           float* __restrict__ spart) {
  const int x = blockIdx.x;
  const int ch = x >> 5, k = x & 31;
  const int t = threadIdx.x;
  const int wave = t >> 6, lane = t & 63;
  const int g = lane >> 4, r = lane & 15;
  const int b = wave * 16 + r;
  const int j0 = ch * JCB;

  const unsigned short* wp = WB + ((size_t)j0 * 32 + k) * 256 + r * 16 + 4 * g;
  const unsigned short* xp = XT + ((size_t)j0 * 64 + b) * 16 + 4 * g;
  const float* cp = cB + ((size_t)j0 * 64 + b) * 32 + k;

  f32x4 acc = {0.f, 0.f, 0.f, 0.f};
#pragma unroll 4
  for (int jc = 0; jc < JCB; ++jc) {
    const uint2 wv = *(const uint2*)(wp + jc * 8192);
    const uint2 xv = *(const uint2*)(xp + jc * 1024);
    short8v bfr;
    if constexpr (CMODE == 1) {
      const float c = cp[jc * 2048];
      const unsigned int p0 = f2bf(bf2f(xv.x & 0xffffu) * c) |
                              (f2bf(bf2f(xv.x >> 16) * c) << 16);
      const unsigned int p1 = f2bf(bf2f(xv.y & 0xffffu) * c) |
                              (f2bf(bf2f(xv.y >> 16) * c) << 16);
      bfr = mk_frag(p0, p1);
    } else {
      bfr = mk_frag(xv.x, xv.y);
    }
    acc = __builtin_amdgcn_mfma_f32_16x16x32_bf16(mk_frag(wv.x, wv.y), bfr, acc, 0, 0, 0);
  }
  const float sc = (CMODE == 0) ? (1.f / 32.f) : 1.f;
  // C layout: col = b (lane&15), row = d = 4g + reg  ->  16B contiguous store
  *(float4*)(spart + (((size_t)b * CHB + ch) * 32 + k) * 16 + 4 * g) =
      make_float4(acc[0] * sc, acc[1] * sc, acc[2] * sc, acc[3] * sc);
}

// ---------------- squash: reduce spart -> s, squash -> o; keep f32 osum + bf16 mirror.
__global__ __launch_bounds__(256) void k_squash(const float* __restrict__ spart,
                                                float* __restrict__ osum,
                                                unsigned short* __restrict__ osum_bf,
                                                float* __restrict__ outp,
                                                int first, int final_) {
  const int t = threadIdx.x;
  const int wave = t >> 6, lane = t & 63;
  const int gw = blockIdx.x * 4 + wave;   // 0..B_*K_-1
  const int b = gw >> 5, k = gw & 31;
  const int d = lane & 15, pg = lane >> 4;
  float s = 0.f;
  for (int p = pg; p < CHB; p += 4)
    s += spart[(((size_t)b * CHB + p) * 32 + k) * 16 + d];
  s += __shfl_xor(s, 16);
  s += __shfl_xor(s, 32);
  float ss = s * s;
  ss += __shfl_xor(ss, 1); ss += __shfl_xor(ss, 2);
  ss += __shfl_xor(ss, 4); ss += __shfl_xor(ss, 8);
  const float scale = (ss / (1.f + ss)) * rsqrtf(ss + 1e-7f);
  const float ov = scale * s;
  if (final_) {
    if (lane < 16) outp[((size_t)b * K_ + k) * 2064 + d] = ov;
  } else {
    const float prev = first ? 0.f : osum[b * KD + k * 16 + d];
    const float ns = prev + ov;
    const float partner = __shfl_xor(ns, 1);
    if (lane < 16) {
      osum[b * KD + k * 16 + d] = ns;
      if (!(lane & 1)) {
        const unsigned int pk = f2bf(ns) | (f2bf(partner) << 16);
        *(unsigned int*)(osum_bf + b * KD + k * 16 + d) = pk;
      }
    }
  }
}

extern "C" void kernel_launch(void* const* d_in, const int* in_sizes, int n_in,
                              void* d_out, int out_size, void* d_ws, size_t ws_size,
                              hipStream_t stream) {
  const float* inp = (const float*)d_in[0];   // [64,2048,16]
  const float* W   = (const float*)d_in[1];   // [32,2048,16,16]
  float* outp = (float*)d_out;                // [64,32,2064]
  char* ws = (char*)d_ws;
  // ws: WB 32M | XT 4M | cB 16M | spart 16M | osum 128K | osum_bf 64K  (~68.2 MiB)
  unsigned short* WB = (unsigned short*)ws;
  unsigned short* XT = (unsigned short*)(ws + (size_t)33554432);
  float* cB    = (float*)(ws + (size_t)33554432 + 4194304);
  float* spart = (float*)(ws + (size_t)33554432 + 4194304 + 16777216);
  float* osum  = (float*)(ws + (size_t)33554432 + 4194304 + 16777216 + 16777216);
  unsigned short* osum_bf =
      (unsigned short*)(ws + (size_t)33554432 + 4194304 + 16777216 + 16777216 + 131072);

  k_prep<<<2048, 256, 0, stream>>>(inp, W, WB, XT);
  // iter 0: c = 1/32
  k_B<0><<<CHB * K_, 256, 0, stream>>>(XT, WB, nullptr, spart);
  k_squash<<<B_ * K_ / 4, 256, 0, stream>>>(spart, osum, osum_bf, outp, 1, 0);
  // iter 1
  k_A<0><<<J_ / JCA, 256, 0, stream>>>(XT, WB, osum_bf, cB, nullptr);
  k_B<1><<<CHB * K_, 256, 0, stream>>>(XT, WB, cB, spart);
  k_squash<<<B_ * K_ / 4, 256, 0, stream>>>(spart, osum, osum_bf, outp, 0, 0);
  // iter 2 (final): c to outp, o to outp
  k_A<1><<<J_ / JCA, 256, 0, stream>>>(XT, WB, osum_bf, cB, outp);
  k_B<1><<<CHB * K_, 256, 0, stream>>>(XT, WB, cB, spart);
  k_squash<<<B_ * K_ / 4, 256, 0, stream>>>(spart, osum, osum_bf, outp, 0, 1);
}